// Round 12
// baseline (238.210 us; speedup 1.0000x reference)
//
#include <hip/hip_runtime.h>
#include <hip/hip_bf16.h>
#include <stdint.h>

// ---------------------------------------------------------------------------
// simple_GCN: 3-layer GCNConv (N=10000, E=160000, 128->1000->700->200) +
// global mean pool (64 graphs) + linear(10).
//
// R12: dead-column elimination in the aggregations. Layer-2 pad chunks
// (88..95, feats 704..767) are identically zero -> write zeros, skip the
// gather (GEMM3's K-band stays valid). Layer-3 pad chunks (25..31) are
// never read by pool -> skip entirely. Bit-identical output. Everything
// else as R11: slot CSR, XCD feature panels, split-2 + pipelined int4 quad
// gathers, BK=64 + XOR-swizzled MFMA GEMMs with row-banded XCD mapping.
// ---------------------------------------------------------------------------

#define SLOT 64

__device__ __forceinline__ uint16_t f2b(float f) {           // fp32->bf16 RNE
    union { float f; uint32_t u; } v; v.f = f;
    return (uint16_t)((v.u + 0x7fffu + ((v.u >> 16) & 1u)) >> 16);
}
__device__ __forceinline__ float blo(uint32_t u) { union { uint32_t u; float f; } v; v.u = u << 16; return v.f; }
__device__ __forceinline__ float bhi(uint32_t u) { union { uint32_t u; float f; } v; v.u = u & 0xffff0000u; return v.f; }

// ---------------- slot CSR: one-pass count + placement ----------------
__global__ void k_scatter(const int* __restrict__ src, const int* __restrict__ dst,
                          int* __restrict__ cursor, int* __restrict__ slots, int E) {
    int e = blockIdx.x * blockDim.x + threadIdx.x;
    if (e < E) {
        int s = src[e], d = dst[e];
        int pos = atomicAdd(&cursor[d], 1);
        if (pos < SLOT) slots[d * SLOT + pos] = s;
    }
}

// ---------------- merged prep: wt3 (z<3) + biaspad (z=3) + cvt (z=4) + dinv (z=5)
__global__ void k_prep(const float* __restrict__ W1, const float* __restrict__ W2,
                       const float* __restrict__ W3,
                       uint16_t* __restrict__ T1, uint16_t* __restrict__ T2,
                       uint16_t* __restrict__ T3,
                       const float* __restrict__ b1, const float* __restrict__ b2,
                       const float* __restrict__ b3,
                       float* __restrict__ p1, float* __restrict__ p2,
                       float* __restrict__ p3,
                       const float* __restrict__ x, uint16_t* __restrict__ xb,
                       const int* __restrict__ deg, float* __restrict__ dinv,
                       int N, int F, int H1, int H2, int H3,
                       int Fp, int H1p, int H2p, int H3p, int n8) {
    __shared__ float tile[32][33];
    int z = blockIdx.z;
    if (z < 3) {
        const float* W; uint16_t* T; int K, Nn, Kp, Np;
        if (z == 0)      { W = W1; T = T1; K = F;  Nn = H1; Kp = Fp;  Np = H1p; }
        else if (z == 1) { W = W2; T = T2; K = H1; Nn = H2; Kp = H1p; Np = H2p; }
        else             { W = W3; T = T3; K = H2; Nn = H3; Kp = H2p; Np = H3p; }
        if ((int)blockIdx.x * 32 >= Kp || (int)blockIdx.y * 32 >= Np) return;
        int k0 = blockIdx.x * 32, n0 = blockIdx.y * 32;
        int tx = threadIdx.x, ty = threadIdx.y;  // 32 x 8
        for (int i = ty; i < 32; i += 8) {
            int k = k0 + i, n = n0 + tx;
            tile[i][tx] = (k < K && n < Nn) ? W[(size_t)k * Nn + n] : 0.f;
        }
        __syncthreads();
        for (int i = ty; i < 32; i += 8) {
            int n = n0 + i, k = k0 + tx;
            T[(size_t)n * Kp + k] = f2b(tile[tx][i]);
        }
    } else {
        int id = (blockIdx.y * gridDim.x + blockIdx.x) * 256 + threadIdx.y * 32 + threadIdx.x;
        if (z == 3) {
            if (id < H1p) p1[id] = (id < H1) ? b1[id] : 0.f;
            else if (id < H1p + H2p) { int k = id - H1p; p2[k] = (k < H2) ? b2[k] : 0.f; }
            else if (id < H1p + H2p + H3p) { int k = id - H1p - H2p; p3[k] = (k < H3) ? b3[k] : 0.f; }
        } else if (z == 4) {
            if (id < n8) {
                const float4* x4 = (const float4*)x;
                float4 a = x4[2 * id], b = x4[2 * id + 1];
                uint4 o;
                o.x = (uint32_t)f2b(a.x) | ((uint32_t)f2b(a.y) << 16);
                o.y = (uint32_t)f2b(a.z) | ((uint32_t)f2b(a.w) << 16);
                o.z = (uint32_t)f2b(b.x) | ((uint32_t)f2b(b.y) << 16);
                o.w = (uint32_t)f2b(b.z) | ((uint32_t)f2b(b.w) << 16);
                ((uint4*)xb)[id] = o;
            }
        } else {
            if (id < N) dinv[id] = rsqrtf((float)deg[id] + 1.0f);
        }
    }
}

// ---------------- panelized aggregation (split-2, pipelined int4 quads) -----
// HcReal: chunks >= HcReal are pad. padWrite=1 -> write zeros (no gather);
// padWrite=0 -> skip entirely (downstream never reads them).
__global__ __launch_bounds__(256) void k_agg_panel(
    const uint16_t* __restrict__ in, uint16_t* __restrict__ out,
    const int* __restrict__ deg_, const int* __restrict__ slots,
    const float* __restrict__ dinv, const float* __restrict__ bias,
    int N, int Hc, int HcReal, int padWrite, int pc, int P, int relu) {
    int slotg = blockIdx.x & 7;
    int panel = slotg % P;
    int seg   = slotg / P;
    int nseg  = 8 / P;
    int segLen = (N + nseg - 1) / nseg;
    int wave = threadIdx.x >> 6, lane = threadIdx.x & 63;
    int half = lane >> 5, sub = lane & 31;
    int item = (blockIdx.x >> 3) * 128 + wave * 32 + sub;
    int rel = item / pc;
    if (rel >= segLen) return;
    int node = seg * segLen + rel;
    if (node >= N) return;
    int j = panel * pc + (item - rel * pc);
    if (j >= HcReal) {                       // dead pad chunk
        if (padWrite && half == 0)
            ((uint4*)out)[(size_t)node * Hc + j] = (uint4){0u, 0u, 0u, 0u};
        return;
    }
    int deg = deg_[node];
    if (deg > SLOT) deg = SLOT;
    int base = node * SLOT;
    float dv = dinv[node];
    const uint4* in4 = (const uint4*)in;
    float a[8] = {0.f, 0.f, 0.f, 0.f, 0.f, 0.f, 0.f, 0.f};
    if (half == 0) {
        float self = dv * dv;
        uint4 v = in4[(size_t)node * Hc + j];
        a[0] = self * blo(v.x); a[1] = self * bhi(v.x);
        a[2] = self * blo(v.y); a[3] = self * bhi(v.y);
        a[4] = self * blo(v.z); a[5] = self * bhi(v.z);
        a[6] = self * blo(v.w); a[7] = self * bhi(v.w);
    }
    int D8 = deg & ~7;               // full double-quad region
    int e = 4 * half;
    if (e < D8) {
        int4 q = *(const int4*)&slots[base + e];
        uint4 h0 = in4[(size_t)q.x * Hc + j];
        uint4 h1 = in4[(size_t)q.y * Hc + j];
        uint4 h2 = in4[(size_t)q.z * Hc + j];
        uint4 h3 = in4[(size_t)q.w * Hc + j];
        float c0 = dinv[q.x] * dv, c1 = dinv[q.y] * dv;
        float c2 = dinv[q.z] * dv, c3 = dinv[q.w] * dv;
        for (e += 8; e < D8; e += 8) {
            int4 qn = *(const int4*)&slots[base + e];
            uint4 g0 = in4[(size_t)qn.x * Hc + j];
            uint4 g1 = in4[(size_t)qn.y * Hc + j];
            uint4 g2 = in4[(size_t)qn.z * Hc + j];
            uint4 g3 = in4[(size_t)qn.w * Hc + j];
            float d0 = dinv[qn.x] * dv, d1 = dinv[qn.y] * dv;
            float d2 = dinv[qn.z] * dv, d3 = dinv[qn.w] * dv;
            a[0] += c0 * blo(h0.x); a[1] += c0 * bhi(h0.x);
            a[2] += c0 * blo(h0.y); a[3] += c0 * bhi(h0.y);
            a[4] += c0 * blo(h0.z); a[5] += c0 * bhi(h0.z);
            a[6] += c0 * blo(h0.w); a[7] += c0 * bhi(h0.w);
            a[0] += c1 * blo(h1.x); a[1] += c1 * bhi(h1.x);
            a[2] += c1 * blo(h1.y); a[3] += c1 * bhi(h1.y);
            a[4] += c1 * blo(h1.z); a[5] += c1 * bhi(h1.z);
            a[6] += c1 * blo(h1.w); a[7] += c1 * bhi(h1.w);
            a[0] += c2 * blo(h2.x); a[1] += c2 * bhi(h2.x);
            a[2] += c2 * blo(h2.y); a[3] += c2 * bhi(h2.y);
            a[4] += c2 * blo(h2.z); a[5] += c2 * bhi(h2.z);
            a[6] += c2 * blo(h2.w); a[7] += c2 * bhi(h2.w);
            a[0] += c3 * blo(h3.x); a[1] += c3 * bhi(h3.x);
            a[2] += c3 * blo(h3.y); a[3] += c3 * bhi(h3.y);
            a[4] += c3 * blo(h3.z); a[5] += c3 * bhi(h3.z);
            a[6] += c3 * blo(h3.w); a[7] += c3 * bhi(h3.w);
            h0 = g0; h1 = g1; h2 = g2; h3 = g3;
            c0 = d0; c1 = d1; c2 = d2; c3 = d3;
        }
        a[0] += c0 * blo(h0.x); a[1] += c0 * bhi(h0.x);
        a[2] += c0 * blo(h0.y); a[3] += c0 * bhi(h0.y);
        a[4] += c0 * blo(h0.z); a[5] += c0 * bhi(h0.z);
        a[6] += c0 * blo(h0.w); a[7] += c0 * bhi(h0.w);
        a[0] += c1 * blo(h1.x); a[1] += c1 * bhi(h1.x);
        a[2] += c1 * blo(h1.y); a[3] += c1 * bhi(h1.y);
        a[4] += c1 * blo(h1.z); a[5] += c1 * bhi(h1.z);
        a[6] += c1 * blo(h1.w); a[7] += c1 * bhi(h1.w);
        a[0] += c2 * blo(h2.x); a[1] += c2 * bhi(h2.x);
        a[2] += c2 * blo(h2.y); a[3] += c2 * bhi(h2.y);
        a[4] += c2 * blo(h2.z); a[5] += c2 * bhi(h2.z);
        a[6] += c2 * blo(h2.w); a[7] += c2 * bhi(h2.w);
        a[0] += c3 * blo(h3.x); a[1] += c3 * bhi(h3.x);
        a[2] += c3 * blo(h3.y); a[3] += c3 * bhi(h3.y);
        a[4] += c3 * blo(h3.z); a[5] += c3 * bhi(h3.z);
        a[6] += c3 * blo(h3.w); a[7] += c3 * bhi(h3.w);
    }
    // tail [D8, deg): half 0 takes up to 4, half 1 the rest
    int t0 = half ? (D8 + 4 < deg ? D8 + 4 : deg) : D8;
    int t1 = half ? deg : (D8 + 4 < deg ? D8 + 4 : deg);
    for (int ee = t0; ee < t1; ++ee) {
        int s0 = slots[base + ee];
        uint4 h = in4[(size_t)s0 * Hc + j];
        float c = dinv[s0] * dv;
        a[0] += c * blo(h.x); a[1] += c * bhi(h.x);
        a[2] += c * blo(h.y); a[3] += c * bhi(h.y);
        a[4] += c * blo(h.z); a[5] += c * bhi(h.z);
        a[6] += c * blo(h.w); a[7] += c * bhi(h.w);
    }
#pragma unroll
    for (int t = 0; t < 8; ++t) a[t] += __shfl_xor(a[t], 32, 64);
    if (half == 0) {
        if (bias) {
            const float4* b4 = (const float4*)bias;
            float4 b0 = b4[2 * j], b1 = b4[2 * j + 1];
            a[0] += b0.x; a[1] += b0.y; a[2] += b0.z; a[3] += b0.w;
            a[4] += b1.x; a[5] += b1.y; a[6] += b1.z; a[7] += b1.w;
        }
        if (relu) {
#pragma unroll
            for (int t = 0; t < 8; ++t) a[t] = fmaxf(a[t], 0.f);
        }
        uint4 o;
        o.x = (uint32_t)f2b(a[0]) | ((uint32_t)f2b(a[1]) << 16);
        o.y = (uint32_t)f2b(a[2]) | ((uint32_t)f2b(a[3]) << 16);
        o.z = (uint32_t)f2b(a[4]) | ((uint32_t)f2b(a[5]) << 16);
        o.w = (uint32_t)f2b(a[6]) | ((uint32_t)f2b(a[7]) << 16);
        ((uint4*)out)[(size_t)node * Hc + j] = o;
    }
}

// ---------------- flat-parallel mean-pool (bf16 input) ----------------------
__global__ __launch_bounds__(256) void k_pool_fast(
    const uint16_t* __restrict__ h, const int* __restrict__ batch,
    float* __restrict__ pooled_sum, int N, int H, int Hp) {
    int j    = threadIdx.x & 63;
    int slot = threadIdx.x >> 6;
    int Hc   = H >> 2;
    if (j >= Hc) return;
    int HcP  = Hp >> 2;
    const uint2* h2 = (const uint2*)h;
    int base = (blockIdx.x * 4 + slot) * 16;
    float a0 = 0.f, a1 = 0.f, a2 = 0.f, a3 = 0.f;
    int gcur = -1;
#pragma unroll 4
    for (int t = 0; t < 16; ++t) {
        int node = base + t;
        if (node < N) {
            int g = batch[node];
            if (g != gcur) {
                if (gcur >= 0) {
                    float* ps = &pooled_sum[(size_t)gcur * H + j * 4];
                    atomicAdd(&ps[0], a0); atomicAdd(&ps[1], a1);
                    atomicAdd(&ps[2], a2); atomicAdd(&ps[3], a3);
                }
                gcur = g; a0 = a1 = a2 = a3 = 0.f;
            }
            uint2 v = h2[(size_t)node * HcP + j];
            a0 += blo(v.x); a1 += bhi(v.x);
            a2 += blo(v.y); a3 += bhi(v.y);
        }
    }
    if (gcur >= 0) {
        float* ps = &pooled_sum[(size_t)gcur * H + j * 4];
        atomicAdd(&ps[0], a0); atomicAdd(&ps[1], a1);
        atomicAdd(&ps[2], a2); atomicAdd(&ps[3], a3);
    }
}

// ---------------- bf16 MFMA GEMMs, BK=64 + XOR swizzle + row-banded XCD -----
typedef __attribute__((ext_vector_type(8))) short short8;
typedef __attribute__((ext_vector_type(4))) float floatx4;

#define LDSP(p) ((__attribute__((address_space(3))) void*)(uintptr_t)(p))
#define GLBP(p) ((const __attribute__((address_space(1))) void*)(uintptr_t)(p))

// 128x128 tile (4x4 frags) — layers 1,2
__global__ __launch_bounds__(256) void k_gemm128(
    const uint16_t* __restrict__ A, const uint16_t* __restrict__ Bt,
    const float* __restrict__ bias, uint16_t* __restrict__ Cout,
    int M, int Kp, int Np, int relu, int nrg, int nr) {
    int bid = blockIdx.x;
    int rsub = bid & 7;
    int t_ = bid >> 3;
    int rg = t_ % nrg, cc = t_ / nrg;
    int rt = rg * 8 + rsub;
    if (rt >= nr) return;
    int row0 = rt * 128, col0 = cc * 128;

    __shared__ uint16_t As[128 * 64];
    __shared__ uint16_t Bs[128 * 64];
    int tid = threadIdx.x;
    int wave = tid >> 6, lane = tid & 63;
    int quad = lane >> 4, m16 = lane & 15;
    int wr = wave >> 1, wc = wave & 1;

    int rA = tid >> 3;
    int cA = (tid & 7) ^ (rA & 7);
    const uint16_t* gA = A  + (size_t)(row0 + rA) * Kp + cA * 8;
    const uint16_t* gB = Bt + (size_t)(col0 + rA) * Kp + cA * 8;
    uint16_t* lA = As + tid * 8;
    uint16_t* lB = Bs + tid * 8;
    size_t rowStep32 = (size_t)32 * Kp;

    floatx4 acc[4][4];
#pragma unroll
    for (int i = 0; i < 4; ++i)
#pragma unroll
        for (int j = 0; j < 4; ++j) acc[i][j] = (floatx4){0.f, 0.f, 0.f, 0.f};

    const short* Ash = (const short*)As;
    const short* Bsh = (const short*)Bs;
    int swA = m16 & 7;

    for (int k0 = 0; k0 < Kp; k0 += 64) {
#pragma unroll
        for (int p = 0; p < 4; ++p) {
            __builtin_amdgcn_global_load_lds(GLBP(gA + p * rowStep32), LDSP(lA + p * 2048), 16, 0, 0);
            __builtin_amdgcn_global_load_lds(GLBP(gB + p * rowStep32), LDSP(lB + p * 2048), 16, 0, 0);
        }
        gA += 64; gB += 64;
        __syncthreads();
#pragma unroll
        for (int h = 0; h < 2; ++h) {
            short8 af[4], bf[4];
            int c = h * 4 + quad;
            int pos = (c ^ swA) * 8;
#pragma unroll
            for (int i = 0; i < 4; ++i)
                af[i] = *(const short8*)&Ash[(wr * 64 + i * 16 + m16) * 64 + pos];
#pragma unroll
            for (int j = 0; j < 4; ++j)
                bf[j] = *(const short8*)&Bsh[(wc * 64 + j * 16 + m16) * 64 + pos];
#pragma unroll
            for (int i = 0; i < 4; ++i)
#pragma unroll
                for (int j = 0; j < 4; ++j)
                    acc[i][j] = __builtin_amdgcn_mfma_f32_16x16x32_bf16(af[i], bf[j], acc[i][j], 0, 0, 0);
        }
        __syncthreads();
    }

    float bv[4];
#pragma unroll
    for (int j = 0; j < 4; ++j) {
        int n = col0 + wc * 64 + j * 16 + m16;
        bv[j] = bias ? bias[n] : 0.f;
    }
#pragma unroll
    for (int i = 0; i < 4; ++i) {
        int mBase = row0 + wr * 64 + i * 16 + quad * 4;
#pragma unroll
        for (int r = 0; r < 4; ++r) {
            int m = mBase + r;
            if (m < M) {
#pragma unroll
                for (int j = 0; j < 4; ++j) {
                    int n = col0 + wc * 64 + j * 16 + m16;
                    float v = acc[i][j][r] + bv[j];
                    if (relu) v = fmaxf(v, 0.f);
                    Cout[(size_t)m * Np + n] = f2b(v);
                }
            }
        }
    }
}

// 128x64 tile (4x2 frags) — layer 3
__global__ __launch_bounds__(256) void k_gemm64(
    const uint16_t* __restrict__ A, const uint16_t* __restrict__ Bt,
    const float* __restrict__ bias, uint16_t* __restrict__ Cout,
    int M, int Kp, int Np, int relu, int nrg, int nr) {
    int bid = blockIdx.x;
    int rsub = bid & 7;
    int t_ = bid >> 3;
    int rg = t_ % nrg, cc = t_ / nrg;
    int rt = rg * 8 + rsub;
    if (rt >= nr) return;
    int row0 = rt * 128, col0 = cc * 64;

    __shared__ uint16_t As[128 * 64];
    __shared__ uint16_t Bs[64 * 64];
    int tid = threadIdx.x;
    int wave = tid >> 6, lane = tid & 63;
    int quad = lane >> 4, m16 = lane & 15;
    int wr = wave >> 1, wc = wave & 1;

    int rA = tid >> 3;
    int cA = (tid & 7) ^ (rA & 7);
    const uint16_t* gA = A  + (size_t)(row0 + rA) * Kp + cA * 8;
    const uint16_t* gB = Bt + (size_t)(col0 + rA) * Kp + cA * 8;
    uint16_t* lA = As + tid * 8;
    uint16_t* lB = Bs + tid * 8;
    size_t rowStep32 = (size_t)32 * Kp;

    floatx4 acc[4][2];
#pragma unroll
    for (int i = 0; i < 4; ++i)
#pragma unroll
        for (int j = 0; j < 2; ++j) acc[i][j] = (floatx4){0.f, 0.f, 0.f, 0.f};

    const short* Ash = (const short*)As;
    const short* Bsh = (const short*)Bs;
    int swA = m16 & 7;

    for (int k0 = 0; k0 < Kp; k0 += 64) {
#pragma unroll
        for (int p = 0; p < 4; ++p)
            __builtin_amdgcn_global_load_lds(GLBP(gA + p * rowStep32), LDSP(lA + p * 2048), 16, 0, 0);
#pragma unroll
        for (int p = 0; p < 2; ++p)
            __builtin_amdgcn_global_load_lds(GLBP(gB + p * rowStep32), LDSP(lB + p * 2048), 16, 0, 0);
        gA += 64; gB += 64;
        __syncthreads();
#pragma unroll
        for (int h = 0; h < 2; ++h) {
            short8 af[4], bf[2];
            int c = h * 4 + quad;
            int pos = (c ^ swA) * 8;
#pragma unroll
            for (int i = 0; i < 4; ++i)
                af[i] = *(const short8*)&Ash[(wr * 64 + i * 16 + m16) * 64 + pos];
#pragma unroll
            for (int j = 0; j < 2; ++j)
                bf[j] = *(const short8*)&Bsh[(wc * 32 + j * 16 + m16) * 64 + pos];
#pragma unroll
            for (int i = 0; i < 4; ++i)
#pragma unroll
                for (int j = 0; j < 2; ++j)
                    acc[i][j] = __builtin_amdgcn_mfma_f32_16x16x32_bf16(af[i], bf[j], acc[i][j], 0, 0, 0);
        }
        __syncthreads();
    }

    float bv[2];
#pragma unroll
    for (int j = 0; j < 2; ++j) {
        int n = col0 + wc * 32 + j * 16 + m16;
        bv[j] = bias ? bias[n] : 0.f;
    }
#pragma unroll
    for (int i = 0; i < 4; ++i) {
        int mBase = row0 + wr * 64 + i * 16 + quad * 4;
#pragma unroll
        for (int r = 0; r < 4; ++r) {
            int m = mBase + r;
            if (m < M) {
#pragma unroll
                for (int j = 0; j < 2; ++j) {
                    int n = col0 + wc * 32 + j * 16 + m16;
                    float v = acc[i][j][r] + bv[j];
                    if (relu) v = fmaxf(v, 0.f);
                    Cout[(size_t)m * Np + n] = f2b(v);
                }
            }
        }
    }
}

// ---------------- classifier ----------------
__global__ void k_classifier(const float* __restrict__ pooled_sum,
                             const int* __restrict__ batch,
                             const float* __restrict__ Wl, const float* __restrict__ bl,
                             float* __restrict__ out, int N, int H, int NC) {
    int g = blockIdx.x, c = threadIdx.x;
    int lo = 0, hi = N;
    while (lo < hi) { int mid = (lo + hi) >> 1; if (batch[mid] < g) lo = mid + 1; else hi = mid; }
    int start = lo;
    lo = start; hi = N;
    while (lo < hi) { int mid = (lo + hi) >> 1; if (batch[mid] < g + 1) lo = mid + 1; else hi = mid; }
    int end = lo;
    float scale = 1.0f / fmaxf((float)(end - start), 1.0f);
    if (c < NC) {
        float acc = 0.f;
        for (int k = 0; k < H; ++k) acc += pooled_sum[(size_t)g * H + k] * Wl[(size_t)k * NC + c];
        out[(size_t)g * NC + c] = acc * scale + bl[c];
    }
}

static inline size_t align256(size_t x) { return (x + 255) & ~(size_t)255; }
static inline int pad128(int x) { return (x + 127) & ~127; }

extern "C" void kernel_launch(void* const* d_in, const int* in_sizes, int n_in,
                              void* d_out, int out_size, void* d_ws, size_t ws_size,
                              hipStream_t stream) {
    const float* x   = (const float*)d_in[0];
    const int*   ei  = (const int*)d_in[1];
    const int*   bat = (const int*)d_in[2];
    const float* W1  = (const float*)d_in[3];
    const float* b1  = (const float*)d_in[4];
    const float* W2  = (const float*)d_in[5];
    const float* b2  = (const float*)d_in[6];
    const float* W3  = (const float*)d_in[7];
    const float* b3  = (const float*)d_in[8];
    const float* Wl  = (const float*)d_in[9];
    const float* bl  = (const float*)d_in[10];

    const int N  = in_sizes[2];
    const int E  = in_sizes[1] / 2;
    const int F  = in_sizes[0] / N;    // 128
    const int H1 = in_sizes[4];        // 1000
    const int H2 = in_sizes[6];        // 700
    const int H3 = in_sizes[8];        // 200
    const int NC = in_sizes[10];       // 10
    const int G  = out_size / NC;      // 64
    const int* src = ei;
    const int* dst = ei + E;

    const int Mp  = pad128(N);         // 10112
    const int Fp  = F;                 // 128
    const int H1p = pad128(H1);        // 1024
    const int H2p = pad128(H2);        // 768
    const int H3p = pad128(H3);        // 256
    const int Hc2real = (H2 + 7) / 8;  // 88 real chunks (704 feats) layer 2
    const int Hc3real = (H3 + 7) / 8;  // 25 real chunks (200 feats) layer 3

    // workspace carve (cursor and pooled adjacent -> single memset)
    char* p = (char*)d_ws;
    size_t off = 0;
    auto carve = [&](size_t bytes) { void* q = p + off; off += align256(bytes); return q; };
    uint16_t* xb     = (uint16_t*)carve((size_t)Mp * Fp * 2);
    uint16_t* bufA   = (uint16_t*)carve((size_t)Mp * 2048);
    uint16_t* bufB   = (uint16_t*)carve((size_t)Mp * 2048);
    uint16_t* W1t    = (uint16_t*)carve((size_t)H1p * Fp * 2);
    uint16_t* W2t    = (uint16_t*)carve((size_t)H2p * H1p * 2);
    uint16_t* W3t    = (uint16_t*)carve((size_t)H3p * H2p * 2);
    float* b1p       = (float*)carve((size_t)H1p * 4);
    float* b2p       = (float*)carve((size_t)H2p * 4);
    float* b3p       = (float*)carve((size_t)H3p * 4);
    float* dinv      = (float*)carve((size_t)N * 4);
    int*   cursor    = (int*)carve((size_t)N * 4);
    float* pooled    = (float*)carve((size_t)G * H3 * 4);
    int*   slots     = (int*)carve((size_t)N * SLOT * 4);
    (void)ws_size;

    const int nbE = (E + 255) / 256;

    // ---- zero cursor + pooled in one memset (adjacent carves) ----
    size_t zlen = (size_t)((char*)pooled - (char*)cursor) + (size_t)G * H3 * 4;
    hipMemsetAsync(cursor, 0, zlen, stream);

    // ---- slot CSR: one-pass scatter (count+place) ----
    k_scatter<<<nbE, 256, 0, stream>>>(src, dst, cursor, slots, E);

    // ---- merged prep: weight transposes + bias pads + x->bf16 + dinv ----
    k_prep<<<dim3(32, 32, 6), dim3(32, 8), 0, stream>>>(
        W1, W2, W3, W1t, W2t, W3t, b1, b2, b3, b1p, b2p, b3p, x, xb,
        cursor, dinv, N, F, H1, H2, H3, Fp, H1p, H2p, H3p, N * F / 8);

    // split-2 agg grid: 128 items (=256 threads) per block
    auto agg_grid = [&](int P, int pc) {
        int nseg = 8 / P;
        int segLen = (N + nseg - 1) / nseg;
        return 8 * ((segLen * pc + 127) / 128);
    };

    const int nr  = Mp / 128;          // 79 row tiles
    const int nrg = (nr + 7) / 8;      // 10 row groups

    // ---- layer 1: agg(xb) [N,128] (P=1); GEMM + b1 + relu -> bufB bf16 [Mp,1024]
    k_agg_panel<<<agg_grid(1, 16), 256, 0, stream>>>(
        xb, bufA, cursor, slots, dinv, nullptr, N, 16, 16, 0, 16, 1, 0);
    k_gemm128<<<nrg * 8 * (H1p / 128), 256, 0, stream>>>(
        bufA, W1t, b1p, bufB, N, Fp, H1p, 1, nrg, nr);

    // ---- layer 2: GEMM -> bufA bf16 [Mp,768]; agg (P=8 x 96, 88 real) -> bufB
    k_gemm128<<<nrg * 8 * (H2p / 128), 256, 0, stream>>>(
        bufB, W2t, nullptr, bufA, N, H1p, H2p, 0, nrg, nr);
    k_agg_panel<<<agg_grid(8, 12), 256, 0, stream>>>(
        bufA, bufB, cursor, slots, dinv, b2p, N, 96, Hc2real, 1, 12, 8, 1);

    // ---- layer 3: GEMM (128x64) -> bufA bf16 [Mp,256]; agg (P=4 x 32, 25 real)
    k_gemm64<<<nrg * 8 * (H3p / 64), 256, 0, stream>>>(
        bufB, W3t, nullptr, bufA, N, H2p, H3p, 0, nrg, nr);
    k_agg_panel<<<agg_grid(4, 8), 256, 0, stream>>>(
        bufA, bufB, cursor, slots, dinv, b3p, N, 32, Hc3real, 0, 8, 4, 1);

    // ---- pool (bf16 input) + classifier ----
    k_pool_fast<<<(N + 63) / 64, 256, 0, stream>>>(
        (const uint16_t*)bufB, bat, pooled, N, H3, H3p);
    k_classifier<<<G, 64, 0, stream>>>(pooled, bat, Wl, bl, (float*)d_out, N, H3, NC);
}